// Round 9
// baseline (400.205 us; speedup 1.0000x reference)
//
#include <hip/hip_runtime.h>

#define D 64
#define ALPHA 0.5f
#define FXSCALE 16777216.f   // 2^24 fixed-point quantum for degree accumulation
#define MAXD 56              // padded-CSR slots per segment (P(overflow) ~ 1e-9)

typedef unsigned long long u64;
typedef unsigned char u8;
typedef unsigned short u16;
typedef unsigned int u32;
typedef float f32x4 __attribute__((ext_vector_type(4)));

static __device__ __forceinline__ u16 f2bf(float f) {
    unsigned u = __float_as_uint(f);
    unsigned r = (u + 0x7fffu + ((u >> 16) & 1u)) >> 16;
    return (u16)r;
}
static __device__ __forceinline__ float bf2f(u16 h) {
    return __uint_as_float(((unsigned)h) << 16);
}
static __device__ __forceinline__ float dinv_of(u64 p) {
    float s = (float)(u32)(p & 0xffffffffULL) * (1.f / FXSCALE);
    return (s > 0.f) ? rsqrtf(s) : 0.f;
}

__global__ void zero4_kernel(int4* __restrict__ p, int n4) {
    int i = blockIdx.x * blockDim.x + threadIdx.x;
    if (i < n4) p[i] = make_int4(0, 0, 0, 0);
}

// ============================ PADDED-CSR PATH ============================
// One kernel: packed degree atomics + immediate padded-CSR placement (rank
// from the atomic return) + transform tiles interleaved in the atomic shadow.
// edata slot = (src, w_raw); normalization is factored into y (scale_y) and
// the gather's per-node dinv scalars.
__global__ void fused_degfill_transform_kernel(
        const int* __restrict__ row, const int* __restrict__ col,
        const float* __restrict__ w,
        u64* __restrict__ pk, float2* __restrict__ edp,
        const float* __restrict__ x,
        const float* __restrict__ Ws, const float* __restrict__ Wd,
        u16* __restrict__ y1, u16* __restrict__ y2,
        int N, int E, int t_count, int d_count, int total_blocks) {
    int b = blockIdx.x;
    int t_before = (int)(((long long)b * t_count) / total_blocks);
    bool is_t = (int)(((long long)(b + 1) * t_count) / total_blocks) > t_before;

    if (!is_t) {
        // ---- degree + histogram + padded fill ----
        int d_idx = b - t_before;
        int stride = d_count * blockDim.x;
        for (int e = d_idx * blockDim.x + threadIdx.x; e < E; e += stride) {
            int r = row[e], c = col[e];
            float we = w[e];
            u64 v = (1ULL << 32) | (u64)__float2uint_rn(we * FXSCALE);
            u64 o1 = atomicAdd(&pk[r], v);
            int rk1 = (int)(o1 >> 32);
            if (rk1 < MAXD)
                edp[(size_t)r * MAXD + rk1] = make_float2(__int_as_float(c), we);
            u64 o2 = atomicAdd(&pk[N + c], v);
            int rk2 = (int)(o2 >> 32);
            if (rk2 < MAXD)
                edp[(size_t)(N + c) * MAXD + rk2] = make_float2(__int_as_float(r), we);
        }
        return;
    }

    // ---- transform role: y1 = bf16(ALPHA*x@Ws^T), y2 = bf16((1-a)*x@Wd^T)
    // shfl-based (33 KB LDS -> 4 blocks/CU); 4 waves x 16 rows per tile.
    __shared__ float Wt1[64][65];   // Wt[k][o], stride 65: conflict-free
    __shared__ float Wt2[64][65];
    int t = threadIdx.x;
    for (int i = t; i < 4096; i += 256) {
        int o = i >> 6, k = i & 63;
        Wt1[k][o] = Ws[i];
        Wt2[k][o] = Wd[i];
    }
    __syncthreads();
    int wv = t >> 6, lane = t & 63;
    int r0 = t_before * 64 + wv * 16;
    for (int rr = 0; rr < 16; ++rr) {
        int gr = r0 + rr;
        if (gr >= N) break;
        float xv = x[(size_t)gr * D + lane];
        float s1 = 0.f, s2 = 0.f;
#pragma unroll
        for (int k = 0; k < 64; ++k) {
            float xb = __shfl(xv, k);
            s1 += xb * Wt1[k][lane];
            s2 += xb * Wt2[k][lane];
        }
        y1[(size_t)gr * D + lane] = f2bf(ALPHA * s1);
        y2[(size_t)gr * D + lane] = f2bf((1.f - ALPHA) * s2);
    }
}

// fold normalization into y: y1[c] *= dinv_in(c), y2[r] *= dinv_out(r)
__global__ void scale_y_kernel(const u64* __restrict__ pk,
                               u16* __restrict__ y1, u16* __restrict__ y2, int N) {
    int i = blockIdx.x * blockDim.x + threadIdx.x;   // quad index: 16 per node
    if (i >= N * 16) return;
    int node = i >> 4;
    float di = dinv_of(pk[N + node]);   // in-degree  -> scales y1 (fwd src)
    float dd = dinv_of(pk[node]);       // out-degree -> scales y2 (bwd src)
    u64* p1 = (u64*)y1 + i;
    u64* p2 = (u64*)y2 + i;
    u64 q1 = *p1, q2 = *p2;
    u64 o1 = 0, o2 = 0;
#pragma unroll
    for (int j = 0; j < 4; ++j) {
        o1 |= (u64)f2bf(bf2f((u16)(q1 >> (16 * j))) * di) << (16 * j);
        o2 |= (u64)f2bf(bf2f((u16)(q2 >> (16 * j))) * dd) << (16 * j);
    }
    *p1 = o1;
    *p2 = o2;
}

// one wave per node; 64 lanes = 4 edge-slots x 16 feature-slots.
// fwd/bwd kept in separate accumulators, combined with per-node dinv scalars.
__global__ void gather_padded_kernel(const u64* __restrict__ pk, const float2* __restrict__ edp,
                                     const u16* __restrict__ y1, const u16* __restrict__ y2,
                                     const float* __restrict__ b_src, const float* __restrict__ b_dst,
                                     float* __restrict__ out, int N) {
    int tid = threadIdx.x;
    int lane = tid & 63;
    int node = blockIdx.x * (blockDim.x >> 6) + (tid >> 6);
    if (node >= N) return;
    int g  = lane >> 4;
    int fl = lane & 15;

    u64 pf = pk[node], pb = pk[N + node];
    int cf = min((int)(pf >> 32), MAXD);
    int cb = min((int)(pb >> 32), MAXD);
    float dout = dinv_of(pf);   // scales fwd aggregate
    float din  = dinv_of(pb);   // scales bwd aggregate

    float f0 = 0.f, f1 = 0.f, f2 = 0.f, f3 = 0.f;
    float b0 = 0.f, b1 = 0.f, b2 = 0.f, b3 = 0.f;

    {   // forward: dst=node, srcs in edp[node*MAXD .. +cf)
        const float2* seg = edp + (size_t)node * MAXD;
        for (int eb = 0; eb < cf; eb += 8) {
            int ea = eb + g, ex = eb + 4 + g;
            float2 da = (ea < cf) ? seg[ea] : make_float2(__int_as_float(0), 0.f);
            float2 db = (ex < cf) ? seg[ex] : make_float2(__int_as_float(0), 0.f);
            int sa = __float_as_int(da.x), sb = __float_as_int(db.x);
            float wa = da.y, wb = db.y;
            u64 qa = *(const u64*)(y1 + (((size_t)sa) << 6) + (fl << 2));
            u64 qb = *(const u64*)(y1 + (((size_t)sb) << 6) + (fl << 2));
            f0 += wa * bf2f((u16)qa)         + wb * bf2f((u16)qb);
            f1 += wa * bf2f((u16)(qa >> 16)) + wb * bf2f((u16)(qb >> 16));
            f2 += wa * bf2f((u16)(qa >> 32)) + wb * bf2f((u16)(qb >> 32));
            f3 += wa * bf2f((u16)(qa >> 48)) + wb * bf2f((u16)(qb >> 48));
        }
    }
    {   // backward: dst=node, srcs in edp[(N+node)*MAXD .. +cb)
        const float2* seg = edp + (size_t)(N + node) * MAXD;
        for (int eb = 0; eb < cb; eb += 8) {
            int ea = eb + g, ex = eb + 4 + g;
            float2 da = (ea < cb) ? seg[ea] : make_float2(__int_as_float(0), 0.f);
            float2 db = (ex < cb) ? seg[ex] : make_float2(__int_as_float(0), 0.f);
            int sa = __float_as_int(da.x), sb = __float_as_int(db.x);
            float wa = da.y, wb = db.y;
            u64 qa = *(const u64*)(y2 + (((size_t)sa) << 6) + (fl << 2));
            u64 qb = *(const u64*)(y2 + (((size_t)sb) << 6) + (fl << 2));
            b0 += wa * bf2f((u16)qa)         + wb * bf2f((u16)qb);
            b1 += wa * bf2f((u16)(qa >> 16)) + wb * bf2f((u16)(qb >> 16));
            b2 += wa * bf2f((u16)(qa >> 32)) + wb * bf2f((u16)(qb >> 32));
            b3 += wa * bf2f((u16)(qa >> 48)) + wb * bf2f((u16)(qb >> 48));
        }
    }
    // combine directions (wave-uniform scalars), then reduce the 4 edge groups
    float v0 = f0 * dout + b0 * din;
    float v1 = f1 * dout + b1 * din;
    float v2 = f2 * dout + b2 * din;
    float v3 = f3 * dout + b3 * din;
    v0 += __shfl_xor(v0, 16); v0 += __shfl_xor(v0, 32);
    v1 += __shfl_xor(v1, 16); v1 += __shfl_xor(v1, 32);
    v2 += __shfl_xor(v2, 16); v2 += __shfl_xor(v2, 32);
    v3 += __shfl_xor(v3, 16); v3 += __shfl_xor(v3, 32);
    if (g == 0) {
        float4 bs = *(const float4*)&b_src[fl << 2];
        float4 bd = *(const float4*)&b_dst[fl << 2];
        f32x4 o;
        o.x = v0 + ALPHA * bs.x + (1.f - ALPHA) * bd.x;
        o.y = v1 + ALPHA * bs.y + (1.f - ALPHA) * bd.y;
        o.z = v2 + ALPHA * bs.z + (1.f - ALPHA) * bd.z;
        o.w = v3 + ALPHA * bs.w + (1.f - ALPHA) * bd.w;
        __builtin_nontemporal_store(o, (f32x4*)&out[((size_t)node << 6) + (fl << 2)]);
    }
}

// ===================== FALLBACK PATH (R8, compact CSR) =====================
__global__ void fused_deg_transform_kernel(
        const int* __restrict__ row, const int* __restrict__ col,
        const float* __restrict__ w,
        u64* __restrict__ pk, u8* __restrict__ rank_f, u8* __restrict__ rank_b,
        const float* __restrict__ x,
        const float* __restrict__ Ws, const float* __restrict__ Wd,
        u16* __restrict__ y1, u16* __restrict__ y2,
        int N, int E, int t_count, int d_count, int total_blocks) {
    int b = blockIdx.x;
    int t_before = (int)(((long long)b * t_count) / total_blocks);
    bool is_t = (int)(((long long)(b + 1) * t_count) / total_blocks) > t_before;
    if (!is_t) {
        int d_idx = b - t_before;
        int stride = d_count * blockDim.x;
        for (int e = d_idx * blockDim.x + threadIdx.x; e < E; e += stride) {
            int r = row[e], c = col[e];
            u64 v = (1ULL << 32) | (u64)__float2uint_rn(w[e] * FXSCALE);
            u64 o1 = atomicAdd(&pk[r], v);
            rank_f[e] = (u8)(o1 >> 32);
            u64 o2 = atomicAdd(&pk[N + c], v);
            rank_b[e] = (u8)(o2 >> 32);
        }
        return;
    }
    __shared__ float Wt1[64][65];
    __shared__ float Wt2[64][65];
    int t = threadIdx.x;
    for (int i = t; i < 4096; i += 256) {
        int o = i >> 6, k = i & 63;
        Wt1[k][o] = Ws[i];
        Wt2[k][o] = Wd[i];
    }
    __syncthreads();
    int wv = t >> 6, lane = t & 63;
    int r0 = t_before * 64 + wv * 16;
    for (int rr = 0; rr < 16; ++rr) {
        int gr = r0 + rr;
        if (gr >= N) break;
        float xv = x[(size_t)gr * D + lane];
        float s1 = 0.f, s2 = 0.f;
#pragma unroll
        for (int k = 0; k < 64; ++k) {
            float xb = __shfl(xv, k);
            s1 += xb * Wt1[k][lane];
            s2 += xb * Wt2[k][lane];
        }
        y1[(size_t)gr * D + lane] = f2bf(ALPHA * s1);
        y2[(size_t)gr * D + lane] = f2bf((1.f - ALPHA) * s2);
    }
}

__global__ void scan1_unpack_kernel(const u64* __restrict__ pk, int* __restrict__ bsum,
                                    float* __restrict__ dinv, int L) {
    __shared__ int s[512];
    int t = threadIdx.x;
    int i = blockIdx.x * 512 + t;
    u64 p = (i < L) ? pk[i] : 0ULL;
    if (i < L) dinv[i] = dinv_of(p);
    s[t] = (int)(p >> 32);
    __syncthreads();
    for (int off = 256; off; off >>= 1) {
        if (t < off) s[t] += s[t + off];
        __syncthreads();
    }
    if (t == 0) bsum[blockIdx.x] = s[0];
}

__global__ void scan2_kernel(int* __restrict__ bsum, int nb) {
    __shared__ int s[512];
    int t = threadIdx.x;
    int v = (t < nb) ? bsum[t] : 0;
    s[t] = v;
    __syncthreads();
    for (int off = 1; off < 512; off <<= 1) {
        int u = (t >= off) ? s[t - off] : 0;
        __syncthreads();
        s[t] += u;
        __syncthreads();
    }
    if (t < nb) bsum[t] = s[t] - v;
}

__global__ void scan3_kernel(const u64* __restrict__ pk, const int* __restrict__ bsum,
                             int* __restrict__ ptr, int L, int total) {
    __shared__ int s[512];
    int t = threadIdx.x;
    int i = blockIdx.x * 512 + t;
    int v = (i < L) ? (int)(pk[i] >> 32) : 0;
    s[t] = v;
    __syncthreads();
    for (int off = 1; off < 512; off <<= 1) {
        int u = (t >= off) ? s[t - off] : 0;
        __syncthreads();
        s[t] += u;
        __syncthreads();
    }
    if (i < L) ptr[i] = bsum[blockIdx.x] + s[t] - v;
    if (i == 0) ptr[L] = total;
}

__global__ void fill_ranked_kernel(const int* __restrict__ row, const int* __restrict__ col,
                                   const float* __restrict__ w,
                                   const float* __restrict__ dinv,
                                   const u8* __restrict__ rank_f, const u8* __restrict__ rank_b,
                                   const int* __restrict__ ptr,
                                   float2* __restrict__ edata,
                                   int N, int E) {
    int e = blockIdx.x * blockDim.x + threadIdx.x;
    if (e >= E) return;
    int r = row[e], c = col[e];
    float wn = w[e] * dinv[r] * dinv[N + c];
    edata[ptr[r] + rank_f[e]]     = make_float2(__int_as_float(c), wn);
    edata[ptr[N + c] + rank_b[e]] = make_float2(__int_as_float(r), wn);
}

__global__ void gather_merged_kernel(const int* __restrict__ ptr, const float2* __restrict__ ed,
                                     const u16* __restrict__ y1, const u16* __restrict__ y2,
                                     const float* __restrict__ b_src, const float* __restrict__ b_dst,
                                     float* __restrict__ out, int N) {
    int tid = threadIdx.x;
    int lane = tid & 63;
    int node = blockIdx.x * (blockDim.x >> 6) + (tid >> 6);
    if (node >= N) return;
    int g  = lane >> 4;
    int fl = lane & 15;
    float a0 = 0.f, a1 = 0.f, a2 = 0.f, a3 = 0.f;
#pragma unroll
    for (int dir = 0; dir < 2; ++dir) {
        const u16* __restrict__ y = dir ? y2 : y1;
        int e0 = ptr[dir ? (N + node) : node];
        int e1 = ptr[(dir ? (N + node) : node) + 1];
        for (int eb = e0; eb < e1; eb += 8) {
            int ea = eb + g, ex = eb + 4 + g;
            float2 da = (ea < e1) ? ed[ea] : make_float2(__int_as_float(0), 0.f);
            float2 db = (ex < e1) ? ed[ex] : make_float2(__int_as_float(0), 0.f);
            int sa = __float_as_int(da.x), sb = __float_as_int(db.x);
            float wa = da.y, wb = db.y;
            u64 qa = *(const u64*)(y + (((size_t)sa) << 6) + (fl << 2));
            u64 qb = *(const u64*)(y + (((size_t)sb) << 6) + (fl << 2));
            a0 += wa * bf2f((u16)qa)         + wb * bf2f((u16)qb);
            a1 += wa * bf2f((u16)(qa >> 16)) + wb * bf2f((u16)(qb >> 16));
            a2 += wa * bf2f((u16)(qa >> 32)) + wb * bf2f((u16)(qb >> 32));
            a3 += wa * bf2f((u16)(qa >> 48)) + wb * bf2f((u16)(qb >> 48));
        }
    }
    a0 += __shfl_xor(a0, 16); a0 += __shfl_xor(a0, 32);
    a1 += __shfl_xor(a1, 16); a1 += __shfl_xor(a1, 32);
    a2 += __shfl_xor(a2, 16); a2 += __shfl_xor(a2, 32);
    a3 += __shfl_xor(a3, 16); a3 += __shfl_xor(a3, 32);
    if (g == 0) {
        float4 bs = *(const float4*)&b_src[fl << 2];
        float4 bd = *(const float4*)&b_dst[fl << 2];
        f32x4 o;
        o.x = a0 + ALPHA * bs.x + (1.f - ALPHA) * bd.x;
        o.y = a1 + ALPHA * bs.y + (1.f - ALPHA) * bd.y;
        o.z = a2 + ALPHA * bs.z + (1.f - ALPHA) * bd.z;
        o.w = a3 + ALPHA * bs.w + (1.f - ALPHA) * bd.w;
        __builtin_nontemporal_store(o, (f32x4*)&out[((size_t)node << 6) + (fl << 2)]);
    }
}

extern "C" void kernel_launch(void* const* d_in, const int* in_sizes, int n_in,
                              void* d_out, int out_size, void* d_ws, size_t ws_size,
                              hipStream_t stream) {
    const float* x     = (const float*)d_in[0];
    const int*   ei    = (const int*)d_in[1];
    const float* w     = (const float*)d_in[2];
    const float* W_src = (const float*)d_in[3];
    const float* b_src = (const float*)d_in[4];
    const float* W_dst = (const float*)d_in[5];
    const float* b_dst = (const float*)d_in[6];
    float* out = (float*)d_out;

    const int N = in_sizes[0] / D;
    const int E = in_sizes[2];
    const int* row = ei;
    const int* col = ei + E;
    const int L = 2 * N;
    const int t_count = (N + 63) / 64;
    const int d_count = 2048;
    const int total_blocks = t_count + d_count;

    // ---- try padded-CSR layout: pk | y1 | y2 | edp  (~119 MB) ----
    {
        char* base = (char*)d_ws;
        size_t o = 0;
        auto take = [&](size_t b) { char* p = base + o; o = (o + b + 63) & ~(size_t)63; return p; };
        u64*    pk  = (u64*)take((size_t)L * 8);
        u16*    y1  = (u16*)take((size_t)N * D * 2);
        u16*    y2  = (u16*)take((size_t)N * D * 2);
        float2* edp = (float2*)take((size_t)L * MAXD * 8);
        if (o <= ws_size) {
            zero4_kernel<<<(N + 255) / 256, 256, 0, stream>>>((int4*)pk, N);
            fused_degfill_transform_kernel<<<total_blocks, 256, 0, stream>>>(
                row, col, w, pk, edp, x, W_src, W_dst, y1, y2,
                N, E, t_count, d_count, total_blocks);
            scale_y_kernel<<<(N * 16 + 255) / 256, 256, 0, stream>>>(pk, y1, y2, N);
            gather_padded_kernel<<<(N + 3) / 4, 256, 0, stream>>>(pk, edp, y1, y2,
                                                                  b_src, b_dst, out, N);
            return;
        }
    }

    // ---- fallback: R8 compact-CSR pipeline ----
    const int NB = (L + 511) / 512;
    char* base = (char*)d_ws;
    size_t o = 0;
    auto take = [&](size_t b) { char* p = base + o; o = (o + b + 15) & ~(size_t)15; return p; };
    u64*    pk     = (u64*)take((size_t)L * 8);
    float*  dinv   = (float*)take((size_t)L * 4);
    int*    ptr    = (int*)take((size_t)(L + 1) * 4);
    int*    bsum   = (int*)take(512 * 4);
    u8*     rank_f = (u8*)take((size_t)E);
    u8*     rank_b = (u8*)take((size_t)E);
    u16*    y1     = (u16*)take((size_t)N * D * 2);
    u16*    y2     = (u16*)take((size_t)N * D * 2);
    float2* edata  = (float2*)take((size_t)2 * E * 8);

    zero4_kernel<<<(N + 255) / 256, 256, 0, stream>>>((int4*)pk, N);
    fused_deg_transform_kernel<<<total_blocks, 256, 0, stream>>>(
        row, col, w, pk, rank_f, rank_b, x, W_src, W_dst, y1, y2,
        N, E, t_count, d_count, total_blocks);
    scan1_unpack_kernel<<<NB, 512, 0, stream>>>(pk, bsum, dinv, L);
    scan2_kernel<<<1, 512, 0, stream>>>(bsum, NB);
    scan3_kernel<<<NB, 512, 0, stream>>>(pk, bsum, ptr, L, 2 * E);
    fill_ranked_kernel<<<(E + 255) / 256, 256, 0, stream>>>(row, col, w, dinv, rank_f, rank_b,
                                                            ptr, edata, N, E);
    gather_merged_kernel<<<(N + 3) / 4, 256, 0, stream>>>(ptr, edata, y1, y2,
                                                          b_src, b_dst, out, N);
}

// Round 10
// 321.965 us; speedup vs baseline: 1.2430x; 1.2430x over previous
//
#include <hip/hip_runtime.h>

#define D 64
#define ALPHA 0.5f
#define FXSCALE 16777216.f   // 2^24 fixed-point quantum for degree accumulation
#define CE 2048              // edges per chunk (P1/P3 block)
#define BSH 9                // log2(nodes per bucket)
#define BN 512               // nodes per bucket

typedef unsigned long long u64;
typedef unsigned short u16;
typedef unsigned int u32;
typedef float f32x4 __attribute__((ext_vector_type(4)));

static __device__ __forceinline__ u16 f2bf(float f) {
    unsigned u = __float_as_uint(f);
    unsigned r = (u + 0x7fffu + ((u >> 16) & 1u)) >> 16;
    return (u16)r;
}
static __device__ __forceinline__ float bf2f(u16 h) {
    return __uint_as_float(((unsigned)h) << 16);
}
static __device__ __forceinline__ float dinv_of_fx(u32 fx) {
    float s = (float)fx * (1.f / FXSCALE);
    return (s > 0.f) ? rsqrtf(s) : 0.f;
}

// P1: per-chunk histogram over buckets (dst in [0,2N), bucket = dst>>9)
__global__ void p1_hist_kernel(const int* __restrict__ row, const int* __restrict__ col,
                               int* __restrict__ bh, int N, int E, int NCH, int NBUCK) {
    __shared__ u32 h[512];
    int t = threadIdx.x, ch = blockIdx.x;
    h[t] = 0;
    __syncthreads();
    int e0 = ch * CE, e1 = min(E, e0 + CE);
    for (int e = e0 + t; e < e1; e += 512) {
        atomicAdd(&h[(u32)row[e] >> BSH], 1u);
        atomicAdd(&h[(u32)(N + col[e]) >> BSH], 1u);
    }
    __syncthreads();
    for (int b = t; b < NBUCK; b += 512)
        bh[(size_t)b * NCH + ch] = (int)h[b];   // bucket-major layout
}

// ---- scans over the [bucket][chunk] count matrix (SZ = NBUCK*NCH) ----
__global__ void scan1i_kernel(const int* __restrict__ src, int* __restrict__ bsum, int SZ) {
    __shared__ int s[512];
    int t = threadIdx.x;
    int i = blockIdx.x * 512 + t;
    s[t] = (i < SZ) ? src[i] : 0;
    __syncthreads();
    for (int off = 256; off; off >>= 1) {
        if (t < off) s[t] += s[t + off];
        __syncthreads();
    }
    if (t == 0) bsum[blockIdx.x] = s[0];
}

__global__ void scan2w_kernel(int* __restrict__ bsum, int nb) {   // nb <= 1024
    __shared__ int s[1024];
    int t = threadIdx.x;
    int v = (t < nb) ? bsum[t] : 0;
    s[t] = v;
    __syncthreads();
    for (int off = 1; off < 1024; off <<= 1) {
        int u = (t >= off) ? s[t - off] : 0;
        __syncthreads();
        s[t] += u;
        __syncthreads();
    }
    if (t < nb) bsum[t] = s[t] - v;   // exclusive block offsets
}

__global__ void scan3i_kernel(const int* __restrict__ src, const int* __restrict__ bsum,
                              int* __restrict__ dst, int SZ) {
    __shared__ int s[512];
    int t = threadIdx.x;
    int i = blockIdx.x * 512 + t;
    int v = (i < SZ) ? src[i] : 0;
    s[t] = v;
    __syncthreads();
    for (int off = 1; off < 512; off <<= 1) {
        int u = (t >= off) ? s[t - off] : 0;
        __syncthreads();
        s[t] += u;
        __syncthreads();
    }
    if (i < SZ) dst[i] = bsum[blockIdx.x] + s[t] - v;
}

// P3: in-LDS counting sort of this chunk's entries by bucket, then coalesced
// per-bucket run writes at offsets from the scanned matrix. Zero global atomics.
// entry u64 = w_bits<<32 | src<<9 | dst_lo9
__global__ void p3_sort_kernel(const int* __restrict__ row, const int* __restrict__ col,
                               const float* __restrict__ w,
                               const int* __restrict__ scanned,
                               u64* __restrict__ ent, int N, int E, int NCH, int NBUCK) {
    __shared__ u64 ebuf[4096];
    __shared__ u16 ebkt[4096];
    __shared__ u32 hc[512], hstart[512], hoff[512];
    __shared__ int s[512];
    int t = threadIdx.x, ch = blockIdx.x;
    hc[t] = 0;
    __syncthreads();
    int e0 = ch * CE, e1 = min(E, e0 + CE);
    // phase 1: count per bucket
    for (int e = e0 + t; e < e1; e += 512) {
        atomicAdd(&hc[(u32)row[e] >> BSH], 1u);
        atomicAdd(&hc[(u32)(N + col[e]) >> BSH], 1u);
    }
    __syncthreads();
    // phase 2: exclusive scan -> local start per bucket
    int v = (int)hc[t];
    s[t] = v;
    __syncthreads();
    for (int off = 1; off < 512; off <<= 1) {
        int u = (t >= off) ? s[t - off] : 0;
        __syncthreads();
        s[t] += u;
        __syncthreads();
    }
    hstart[t] = (u32)(s[t] - v);
    hoff[t]   = (u32)(s[t] - v);
    // reuse hc as this chunk's global base per bucket
    hc[t] = (t < NBUCK) ? (u32)scanned[(size_t)t * NCH + ch] : 0u;
    __syncthreads();
    // phase 3: place entries into LDS, bucket-grouped
    for (int e = e0 + t; e < e1; e += 512) {
        int r = row[e], c = col[e];
        u32 wb = __float_as_uint(w[e]);
        u32 b1 = (u32)r >> BSH;                    // fwd: dst=r, src=c
        u64 q1 = ((u64)wb << 32) | ((u32)c << BSH) | ((u32)r & (BN - 1));
        u32 p1 = atomicAdd(&hoff[b1], 1u);
        ebuf[p1] = q1; ebkt[p1] = (u16)b1;
        u32 d2 = (u32)(N + c);                     // bwd: dst=N+c, src=r
        u32 b2 = d2 >> BSH;
        u64 q2 = ((u64)wb << 32) | ((u32)r << BSH) | (d2 & (BN - 1));
        u32 p2 = atomicAdd(&hoff[b2], 1u);
        ebuf[p2] = q2; ebkt[p2] = (u16)b2;
    }
    __syncthreads();
    // phase 4: stream out — consecutive p within a bucket -> consecutive slots
    int nent = 2 * (e1 - e0);
    for (int p = t; p < nent; p += 512) {
        u32 b = ebkt[p];
        ent[(size_t)hc[b] + (u32)p - hstart[b]] = ebuf[p];
    }
}

// P4: per-bucket node histogram (counts + fixed-point weighted degree), CSR ptr,
// dinv, and edata fill — all scatter confined to an L2-resident bucket window.
__global__ void p4_build_kernel(const u64* __restrict__ ent, const int* __restrict__ scanned,
                                float* __restrict__ dinv, int* __restrict__ ptr,
                                float2* __restrict__ edata,
                                int L, int NCH, int NBUCK, int total) {
    __shared__ u32 cnt[512], fx[512], pstart[512], pfill[512];
    __shared__ int s[512];
    int t = threadIdx.x, b = blockIdx.x;
    int base0 = scanned[(size_t)b * NCH];
    int base1 = (b + 1 < NBUCK) ? scanned[(size_t)(b + 1) * NCH] : total;
    int nE = base1 - base0;
    cnt[t] = 0; fx[t] = 0;
    __syncthreads();
    for (int i = t; i < nE; i += 512) {
        u64 q = ent[base0 + i];
        u32 dlo = (u32)q & (BN - 1);
        float wv = __uint_as_float((u32)(q >> 32));
        atomicAdd(&cnt[dlo], 1u);
        atomicAdd(&fx[dlo], (u32)__float2uint_rn(wv * FXSCALE));
    }
    __syncthreads();
    int v = (int)cnt[t];
    s[t] = v;
    __syncthreads();
    for (int off = 1; off < 512; off <<= 1) {
        int u = (t >= off) ? s[t - off] : 0;
        __syncthreads();
        s[t] += u;
        __syncthreads();
    }
    pstart[t] = (u32)(s[t] - v);
    pfill[t]  = (u32)(s[t] - v);
    int node = b * BN + t;
    if (node < L) {
        dinv[node] = dinv_of_fx(fx[t]);
        ptr[node] = base0 + (int)pstart[t];
    }
    if (b == 0 && t == 0) ptr[L] = total;
    __syncthreads();
    for (int i = t; i < nE; i += 512) {
        u64 q = ent[base0 + i];
        u32 dlo = (u32)q & (BN - 1);
        u32 src = ((u32)q) >> BSH;     // 17-bit src, high bits zero
        float wv = __uint_as_float((u32)(q >> 32));
        u32 pos = atomicAdd(&pfill[dlo], 1u);
        edata[base0 + pos] = make_float2(__int_as_float((int)src), wv);
    }
}

// transform with dinv folded: y1[c] = bf16(a*xWs[c]*dinv_in[c]), y2[r] = bf16((1-a)*xWd[r]*dinv_out[r])
__global__ void transform_kernel(const float* __restrict__ x,
                                 const float* __restrict__ Ws, const float* __restrict__ Wd,
                                 const float* __restrict__ dinv,
                                 u16* __restrict__ y1, u16* __restrict__ y2, int N) {
    __shared__ float Wt1[64][65];
    __shared__ float Wt2[64][65];
    int t = threadIdx.x;
    for (int i = t; i < 4096; i += 256) {
        int o = i >> 6, k = i & 63;
        Wt1[k][o] = Ws[i];
        Wt2[k][o] = Wd[i];
    }
    __syncthreads();
    int wv = t >> 6, lane = t & 63;
    int r0 = blockIdx.x * 64 + wv * 16;
    for (int rr = 0; rr < 16; ++rr) {
        int gr = r0 + rr;
        if (gr >= N) break;
        float xv = x[(size_t)gr * D + lane];
        float s1 = 0.f, s2 = 0.f;
#pragma unroll
        for (int k = 0; k < 64; ++k) {
            float xb = __shfl(xv, k);
            s1 += xb * Wt1[k][lane];
            s2 += xb * Wt2[k][lane];
        }
        float d1 = dinv[N + gr];   // in-degree side -> y1 (fwd src)
        float d2 = dinv[gr];       // out-degree side -> y2 (bwd src)
        y1[(size_t)gr * D + lane] = f2bf(ALPHA * s1 * d1);
        y2[(size_t)gr * D + lane] = f2bf((1.f - ALPHA) * s2 * d2);
    }
}

// gather: one wave per node; 64 lanes = 4 edge-slots x 16 feature-slots.
// fwd/bwd accumulated separately, combined with node-side dinv scalars.
__global__ void gather_csr_kernel(const int* __restrict__ ptr, const float* __restrict__ dinv,
                                  const float2* __restrict__ ed,
                                  const u16* __restrict__ y1, const u16* __restrict__ y2,
                                  const float* __restrict__ b_src, const float* __restrict__ b_dst,
                                  float* __restrict__ out, int N) {
    int tid = threadIdx.x;
    int lane = tid & 63;
    int node = blockIdx.x * (blockDim.x >> 6) + (tid >> 6);
    if (node >= N) return;
    int g  = lane >> 4;
    int fl = lane & 15;
    float dout = dinv[node], din = dinv[N + node];

    float f0 = 0.f, f1 = 0.f, f2 = 0.f, f3 = 0.f;
    float b0 = 0.f, b1 = 0.f, b2 = 0.f, b3 = 0.f;

    {   // forward segment (y1)
        int e0 = ptr[node], e1 = ptr[node + 1];
        for (int eb = e0; eb < e1; eb += 8) {
            int ea = eb + g, ex = eb + 4 + g;
            float2 da = (ea < e1) ? ed[ea] : make_float2(__int_as_float(0), 0.f);
            float2 db = (ex < e1) ? ed[ex] : make_float2(__int_as_float(0), 0.f);
            int sa = __float_as_int(da.x), sb = __float_as_int(db.x);
            float wa = da.y, wb = db.y;
            u64 qa = *(const u64*)(y1 + (((size_t)sa) << 6) + (fl << 2));
            u64 qb = *(const u64*)(y1 + (((size_t)sb) << 6) + (fl << 2));
            f0 += wa * bf2f((u16)qa)         + wb * bf2f((u16)qb);
            f1 += wa * bf2f((u16)(qa >> 16)) + wb * bf2f((u16)(qb >> 16));
            f2 += wa * bf2f((u16)(qa >> 32)) + wb * bf2f((u16)(qb >> 32));
            f3 += wa * bf2f((u16)(qa >> 48)) + wb * bf2f((u16)(qb >> 48));
        }
    }
    {   // backward segment (y2)
        int e0 = ptr[N + node], e1 = ptr[N + node + 1];
        for (int eb = e0; eb < e1; eb += 8) {
            int ea = eb + g, ex = eb + 4 + g;
            float2 da = (ea < e1) ? ed[ea] : make_float2(__int_as_float(0), 0.f);
            float2 db = (ex < e1) ? ed[ex] : make_float2(__int_as_float(0), 0.f);
            int sa = __float_as_int(da.x), sb = __float_as_int(db.x);
            float wa = da.y, wb = db.y;
            u64 qa = *(const u64*)(y2 + (((size_t)sa) << 6) + (fl << 2));
            u64 qb = *(const u64*)(y2 + (((size_t)sb) << 6) + (fl << 2));
            b0 += wa * bf2f((u16)qa)         + wb * bf2f((u16)qb);
            b1 += wa * bf2f((u16)(qa >> 16)) + wb * bf2f((u16)(qb >> 16));
            b2 += wa * bf2f((u16)(qa >> 32)) + wb * bf2f((u16)(qb >> 32));
            b3 += wa * bf2f((u16)(qa >> 48)) + wb * bf2f((u16)(qb >> 48));
        }
    }
    float v0 = f0 * dout + b0 * din;
    float v1 = f1 * dout + b1 * din;
    float v2 = f2 * dout + b2 * din;
    float v3 = f3 * dout + b3 * din;
    v0 += __shfl_xor(v0, 16); v0 += __shfl_xor(v0, 32);
    v1 += __shfl_xor(v1, 16); v1 += __shfl_xor(v1, 32);
    v2 += __shfl_xor(v2, 16); v2 += __shfl_xor(v2, 32);
    v3 += __shfl_xor(v3, 16); v3 += __shfl_xor(v3, 32);
    if (g == 0) {
        float4 bs = *(const float4*)&b_src[fl << 2];
        float4 bd = *(const float4*)&b_dst[fl << 2];
        f32x4 o;
        o.x = v0 + ALPHA * bs.x + (1.f - ALPHA) * bd.x;
        o.y = v1 + ALPHA * bs.y + (1.f - ALPHA) * bd.y;
        o.z = v2 + ALPHA * bs.z + (1.f - ALPHA) * bd.z;
        o.w = v3 + ALPHA * bs.w + (1.f - ALPHA) * bd.w;
        __builtin_nontemporal_store(o, (f32x4*)&out[((size_t)node << 6) + (fl << 2)]);
    }
}

extern "C" void kernel_launch(void* const* d_in, const int* in_sizes, int n_in,
                              void* d_out, int out_size, void* d_ws, size_t ws_size,
                              hipStream_t stream) {
    const float* x     = (const float*)d_in[0];
    const int*   ei    = (const int*)d_in[1];
    const float* w     = (const float*)d_in[2];
    const float* W_src = (const float*)d_in[3];
    const float* b_src = (const float*)d_in[4];
    const float* W_dst = (const float*)d_in[5];
    const float* b_dst = (const float*)d_in[6];
    float* out = (float*)d_out;

    const int N = in_sizes[0] / D;
    const int E = in_sizes[2];
    const int* row = ei;
    const int* col = ei + E;
    const int L = 2 * N;
    const int NCH   = (E + CE - 1) / CE;          // chunks (782)
    const int NBUCK = (L + BN - 1) >> BSH;        // buckets (391), must be <= 512
    const int SZ    = NBUCK * NCH;                // count-matrix size (~306k)
    const int NSB   = (SZ + 511) / 512;           // scan blocks (598), must be <= 1024
    const int total = 2 * E;

    // workspace layout (~81 MB)
    char* base = (char*)d_ws;
    size_t o = 0;
    auto take = [&](size_t b) { char* p = base + o; o = (o + b + 63) & ~(size_t)63; return p; };
    int*    bh      = (int*)take((size_t)SZ * 4);
    int*    scanned = (int*)take((size_t)SZ * 4);
    int*    bsum    = (int*)take(1024 * 4);
    u64*    ent     = (u64*)take((size_t)total * 8);
    float*  dinv    = (float*)take((size_t)L * 4);
    int*    ptr     = (int*)take((size_t)(L + 1) * 4);
    u16*    y1      = (u16*)take((size_t)N * D * 2);
    u16*    y2      = (u16*)take((size_t)N * D * 2);
    float2* edata   = (float2*)take((size_t)total * 8);

    // 1. bucket histogram per chunk (LDS atomics only)
    p1_hist_kernel<<<NCH, 512, 0, stream>>>(row, col, bh, N, E, NCH, NBUCK);
    // 2. exclusive scan of [bucket][chunk] counts
    scan1i_kernel<<<NSB, 512, 0, stream>>>(bh, bsum, SZ);
    scan2w_kernel<<<1, 1024, 0, stream>>>(bsum, NSB);
    scan3i_kernel<<<NSB, 512, 0, stream>>>(bh, bsum, scanned, SZ);
    // 3. chunk-local counting sort -> bucket-major entries, coalesced run writes
    p3_sort_kernel<<<NCH, 512, 0, stream>>>(row, col, w, scanned, ent, N, E, NCH, NBUCK);
    // 4. per-bucket node histogram -> dinv, CSR ptr, edata (L2-local scatter)
    p4_build_kernel<<<NBUCK, 512, 0, stream>>>(ent, scanned, dinv, ptr, edata,
                                               L, NCH, NBUCK, total);
    // 5. transform with src-side dinv folded into y
    transform_kernel<<<(N + 63) / 64, 256, 0, stream>>>(x, W_src, W_dst, dinv, y1, y2, N);
    // 6. gather with node-side dinv, single out write
    gather_csr_kernel<<<(N + 3) / 4, 256, 0, stream>>>(ptr, dinv, edata, y1, y2,
                                                       b_src, b_dst, out, N);
}

// Round 11
// 233.698 us; speedup vs baseline: 1.7125x; 1.3777x over previous
//
#include <hip/hip_runtime.h>

#define D 64
#define ALPHA 0.5f
#define FXSCALE 16777216.f   // 2^24 fixed-point quantum for degree accumulation
#define CE 2048              // edges per chunk (P1/P3 block)
#define BSH 9                // log2(nodes per bucket)
#define BN 512               // nodes per bucket

typedef unsigned long long u64;
typedef unsigned short u16;
typedef unsigned int u32;
typedef float f32x4 __attribute__((ext_vector_type(4)));

static __device__ __forceinline__ u16 f2bf(float f) {
    unsigned u = __float_as_uint(f);
    unsigned r = (u + 0x7fffu + ((u >> 16) & 1u)) >> 16;
    return (u16)r;
}
static __device__ __forceinline__ float bf2f(u16 h) {
    return __uint_as_float(((unsigned)h) << 16);
}
static __device__ __forceinline__ float dinv_of_fx(u32 fx) {
    float s = (float)fx * (1.f / FXSCALE);
    return (s > 0.f) ? rsqrtf(s) : 0.f;
}

// P1: per-chunk histogram over buckets (dst in [0,2N), bucket = dst>>9)
__global__ void p1_hist_kernel(const int* __restrict__ row, const int* __restrict__ col,
                               int* __restrict__ bh, int N, int E, int NCH, int NBUCK) {
    __shared__ u32 h[512];
    int t = threadIdx.x, ch = blockIdx.x;
    h[t] = 0;
    __syncthreads();
    int e0 = ch * CE, e1 = min(E, e0 + CE);
    for (int e = e0 + t; e < e1; e += 512) {
        atomicAdd(&h[(u32)row[e] >> BSH], 1u);
        atomicAdd(&h[(u32)(N + col[e]) >> BSH], 1u);
    }
    __syncthreads();
    for (int b = t; b < NBUCK; b += 512)
        bh[(size_t)b * NCH + ch] = (int)h[b];   // bucket-major layout
}

// ---- scans over the [bucket][chunk] count matrix (SZ = NBUCK*NCH) ----
__global__ void scan1i_kernel(const int* __restrict__ src, int* __restrict__ bsum, int SZ) {
    __shared__ int s[512];
    int t = threadIdx.x;
    int i = blockIdx.x * 512 + t;
    s[t] = (i < SZ) ? src[i] : 0;
    __syncthreads();
    for (int off = 256; off; off >>= 1) {
        if (t < off) s[t] += s[t + off];
        __syncthreads();
    }
    if (t == 0) bsum[blockIdx.x] = s[0];
}

__global__ void scan2w_kernel(int* __restrict__ bsum, int nb) {   // nb <= 1024
    __shared__ int s[1024];
    int t = threadIdx.x;
    int v = (t < nb) ? bsum[t] : 0;
    s[t] = v;
    __syncthreads();
    for (int off = 1; off < 1024; off <<= 1) {
        int u = (t >= off) ? s[t - off] : 0;
        __syncthreads();
        s[t] += u;
        __syncthreads();
    }
    if (t < nb) bsum[t] = s[t] - v;   // exclusive block offsets
}

__global__ void scan3i_kernel(const int* __restrict__ src, const int* __restrict__ bsum,
                              int* __restrict__ dst, int SZ) {
    __shared__ int s[512];
    int t = threadIdx.x;
    int i = blockIdx.x * 512 + t;
    int v = (i < SZ) ? src[i] : 0;
    s[t] = v;
    __syncthreads();
    for (int off = 1; off < 512; off <<= 1) {
        int u = (t >= off) ? s[t - off] : 0;
        __syncthreads();
        s[t] += u;
        __syncthreads();
    }
    if (i < SZ) dst[i] = bsum[blockIdx.x] + s[t] - v;
}

// P3: in-LDS counting sort of this chunk's entries by bucket, then coalesced
// per-bucket run writes at offsets from the scanned matrix. Zero global atomics.
// entry u64 = w_bits<<32 | src<<9 | dst_lo9
__global__ void p3_sort_kernel(const int* __restrict__ row, const int* __restrict__ col,
                               const float* __restrict__ w,
                               const int* __restrict__ scanned,
                               u64* __restrict__ ent, int N, int E, int NCH, int NBUCK) {
    __shared__ u64 ebuf[4096];
    __shared__ u16 ebkt[4096];
    __shared__ u32 hc[512], hstart[512], hoff[512];
    __shared__ int s[512];
    int t = threadIdx.x, ch = blockIdx.x;
    hc[t] = 0;
    __syncthreads();
    int e0 = ch * CE, e1 = min(E, e0 + CE);
    // phase 1: count per bucket
    for (int e = e0 + t; e < e1; e += 512) {
        atomicAdd(&hc[(u32)row[e] >> BSH], 1u);
        atomicAdd(&hc[(u32)(N + col[e]) >> BSH], 1u);
    }
    __syncthreads();
    // phase 2: exclusive scan -> local start per bucket
    int v = (int)hc[t];
    s[t] = v;
    __syncthreads();
    for (int off = 1; off < 512; off <<= 1) {
        int u = (t >= off) ? s[t - off] : 0;
        __syncthreads();
        s[t] += u;
        __syncthreads();
    }
    hstart[t] = (u32)(s[t] - v);
    hoff[t]   = (u32)(s[t] - v);
    // reuse hc as this chunk's global base per bucket
    hc[t] = (t < NBUCK) ? (u32)scanned[(size_t)t * NCH + ch] : 0u;
    __syncthreads();
    // phase 3: place entries into LDS, bucket-grouped
    for (int e = e0 + t; e < e1; e += 512) {
        int r = row[e], c = col[e];
        u32 wb = __float_as_uint(w[e]);
        u32 b1 = (u32)r >> BSH;                    // fwd: dst=r, src=c
        u64 q1 = ((u64)wb << 32) | ((u32)c << BSH) | ((u32)r & (BN - 1));
        u32 p1 = atomicAdd(&hoff[b1], 1u);
        ebuf[p1] = q1; ebkt[p1] = (u16)b1;
        u32 d2 = (u32)(N + c);                     // bwd: dst=N+c, src=r
        u32 b2 = d2 >> BSH;
        u64 q2 = ((u64)wb << 32) | ((u32)r << BSH) | (d2 & (BN - 1));
        u32 p2 = atomicAdd(&hoff[b2], 1u);
        ebuf[p2] = q2; ebkt[p2] = (u16)b2;
    }
    __syncthreads();
    // phase 4: stream out — consecutive p within a bucket -> consecutive slots
    int nent = 2 * (e1 - e0);
    for (int p = t; p < nent; p += 512) {
        u32 b = ebkt[p];
        ent[(size_t)hc[b] + (u32)p - hstart[b]] = ebuf[p];
    }
}

// P4: per-bucket node histogram (counts + fixed-point weighted degree), CSR ptr,
// dinv, and edata fill — all scatter confined to an L2-resident bucket window.
__global__ void p4_build_kernel(const u64* __restrict__ ent, const int* __restrict__ scanned,
                                float* __restrict__ dinv, int* __restrict__ ptr,
                                float2* __restrict__ edata,
                                int L, int NCH, int NBUCK, int total) {
    __shared__ u32 cnt[512], fx[512], pstart[512], pfill[512];
    __shared__ int s[512];
    int t = threadIdx.x, b = blockIdx.x;
    int base0 = scanned[(size_t)b * NCH];
    int base1 = (b + 1 < NBUCK) ? scanned[(size_t)(b + 1) * NCH] : total;
    int nE = base1 - base0;
    cnt[t] = 0; fx[t] = 0;
    __syncthreads();
    for (int i = t; i < nE; i += 512) {
        u64 q = ent[base0 + i];
        u32 dlo = (u32)q & (BN - 1);
        float wv = __uint_as_float((u32)(q >> 32));
        atomicAdd(&cnt[dlo], 1u);
        atomicAdd(&fx[dlo], (u32)__float2uint_rn(wv * FXSCALE));
    }
    __syncthreads();
    int v = (int)cnt[t];
    s[t] = v;
    __syncthreads();
    for (int off = 1; off < 512; off <<= 1) {
        int u = (t >= off) ? s[t - off] : 0;
        __syncthreads();
        s[t] += u;
        __syncthreads();
    }
    pstart[t] = (u32)(s[t] - v);
    pfill[t]  = (u32)(s[t] - v);
    int node = b * BN + t;
    if (node < L) {
        dinv[node] = dinv_of_fx(fx[t]);
        ptr[node] = base0 + (int)pstart[t];
    }
    if (b == 0 && t == 0) ptr[L] = total;
    __syncthreads();
    for (int i = t; i < nE; i += 512) {
        u64 q = ent[base0 + i];
        u32 dlo = (u32)q & (BN - 1);
        u32 src = ((u32)q) >> BSH;     // 17-bit src, high bits zero
        float wv = __uint_as_float((u32)(q >> 32));
        u32 pos = atomicAdd(&pfill[dlo], 1u);
        edata[base0 + pos] = make_float2(__int_as_float((int)src), wv);
    }
}

// transform (register-tiled GEMM, R4 style) with dinv folded at the store:
// y1[c] = bf16(a * (x@Ws^T)[c] * dinv[N+c]),  y2[r] = bf16((1-a) * (x@Wd^T)[r] * dinv[r])
__global__ void transform2r_kernel(const float* __restrict__ x,
                                   const float* __restrict__ Ws, const float* __restrict__ Wd,
                                   const float* __restrict__ dinv,
                                   u16* __restrict__ y1, u16* __restrict__ y2, int N) {
    __shared__ float xs[64][65];
    __shared__ float Wt1[64][68];   // 68*4B = 272B row stride: keeps float4 16B-aligned
    __shared__ float Wt2[64][68];
    int t = threadIdx.x;
    for (int i = t; i < 4096; i += 256) {
        int o = i >> 6, k = i & 63;
        Wt1[k][o] = Ws[i];
        Wt2[k][o] = Wd[i];
    }
    int r0 = blockIdx.x * 64;
    for (int i = t; i < 4096; i += 256) {
        int r = i >> 6, k = i & 63;
        int gr = r0 + r;
        xs[r][k] = (gr < N) ? x[(size_t)gr * D + k] : 0.f;
    }
    __syncthreads();
    int ro = t >> 4, co = t & 15;
    float a1[4][4] = {}, a2[4][4] = {};
#pragma unroll 4
    for (int k = 0; k < 64; ++k) {
        float v0 = xs[ro * 4 + 0][k];
        float v1 = xs[ro * 4 + 1][k];
        float v2 = xs[ro * 4 + 2][k];
        float v3 = xs[ro * 4 + 3][k];
        float4 b1 = *(const float4*)&Wt1[k][co * 4];
        float4 b2 = *(const float4*)&Wt2[k][co * 4];
        a1[0][0] += v0 * b1.x; a1[0][1] += v0 * b1.y; a1[0][2] += v0 * b1.z; a1[0][3] += v0 * b1.w;
        a1[1][0] += v1 * b1.x; a1[1][1] += v1 * b1.y; a1[1][2] += v1 * b1.z; a1[1][3] += v1 * b1.w;
        a1[2][0] += v2 * b1.x; a1[2][1] += v2 * b1.y; a1[2][2] += v2 * b1.z; a1[2][3] += v2 * b1.w;
        a1[3][0] += v3 * b1.x; a1[3][1] += v3 * b1.y; a1[3][2] += v3 * b1.z; a1[3][3] += v3 * b1.w;
        a2[0][0] += v0 * b2.x; a2[0][1] += v0 * b2.y; a2[0][2] += v0 * b2.z; a2[0][3] += v0 * b2.w;
        a2[1][0] += v1 * b2.x; a2[1][1] += v1 * b2.y; a2[1][2] += v1 * b2.z; a2[1][3] += v1 * b2.w;
        a2[2][0] += v2 * b2.x; a2[2][1] += v2 * b2.y; a2[2][2] += v2 * b2.z; a2[2][3] += v2 * b2.w;
        a2[3][0] += v3 * b2.x; a2[3][1] += v3 * b2.y; a2[3][2] += v3 * b2.z; a2[3][3] += v3 * b2.w;
    }
#pragma unroll
    for (int i = 0; i < 4; ++i) {
        int gr = r0 + ro * 4 + i;
        if (gr < N) {
            float d1 = ALPHA * dinv[N + gr];          // y1: fwd src side (in-degree)
            float d2 = (1.f - ALPHA) * dinv[gr];      // y2: bwd src side (out-degree)
            ushort4 o1, o2;
            o1.x = f2bf(a1[i][0] * d1); o1.y = f2bf(a1[i][1] * d1);
            o1.z = f2bf(a1[i][2] * d1); o1.w = f2bf(a1[i][3] * d1);
            o2.x = f2bf(a2[i][0] * d2); o2.y = f2bf(a2[i][1] * d2);
            o2.z = f2bf(a2[i][2] * d2); o2.w = f2bf(a2[i][3] * d2);
            *(ushort4*)&y1[(size_t)gr * D + co * 4] = o1;
            *(ushort4*)&y2[(size_t)gr * D + co * 4] = o2;
        }
    }
}

// gather: one wave per node; 64 lanes = 4 edge-slots x 16 feature-slots.
// fwd/bwd accumulated separately, combined with node-side dinv scalars.
__global__ void gather_csr_kernel(const int* __restrict__ ptr, const float* __restrict__ dinv,
                                  const float2* __restrict__ ed,
                                  const u16* __restrict__ y1, const u16* __restrict__ y2,
                                  const float* __restrict__ b_src, const float* __restrict__ b_dst,
                                  float* __restrict__ out, int N) {
    int tid = threadIdx.x;
    int lane = tid & 63;
    int node = blockIdx.x * (blockDim.x >> 6) + (tid >> 6);
    if (node >= N) return;
    int g  = lane >> 4;
    int fl = lane & 15;
    float dout = dinv[node], din = dinv[N + node];

    float f0 = 0.f, f1 = 0.f, f2 = 0.f, f3 = 0.f;
    float b0 = 0.f, b1 = 0.f, b2 = 0.f, b3 = 0.f;

    {   // forward segment (y1)
        int e0 = ptr[node], e1 = ptr[node + 1];
        for (int eb = e0; eb < e1; eb += 8) {
            int ea = eb + g, ex = eb + 4 + g;
            float2 da = (ea < e1) ? ed[ea] : make_float2(__int_as_float(0), 0.f);
            float2 db = (ex < e1) ? ed[ex] : make_float2(__int_as_float(0), 0.f);
            int sa = __float_as_int(da.x), sb = __float_as_int(db.x);
            float wa = da.y, wb = db.y;
            u64 qa = *(const u64*)(y1 + (((size_t)sa) << 6) + (fl << 2));
            u64 qb = *(const u64*)(y1 + (((size_t)sb) << 6) + (fl << 2));
            f0 += wa * bf2f((u16)qa)         + wb * bf2f((u16)qb);
            f1 += wa * bf2f((u16)(qa >> 16)) + wb * bf2f((u16)(qb >> 16));
            f2 += wa * bf2f((u16)(qa >> 32)) + wb * bf2f((u16)(qb >> 32));
            f3 += wa * bf2f((u16)(qa >> 48)) + wb * bf2f((u16)(qb >> 48));
        }
    }
    {   // backward segment (y2)
        int e0 = ptr[N + node], e1 = ptr[N + node + 1];
        for (int eb = e0; eb < e1; eb += 8) {
            int ea = eb + g, ex = eb + 4 + g;
            float2 da = (ea < e1) ? ed[ea] : make_float2(__int_as_float(0), 0.f);
            float2 db = (ex < e1) ? ed[ex] : make_float2(__int_as_float(0), 0.f);
            int sa = __float_as_int(da.x), sb = __float_as_int(db.x);
            float wa = da.y, wb = db.y;
            u64 qa = *(const u64*)(y2 + (((size_t)sa) << 6) + (fl << 2));
            u64 qb = *(const u64*)(y2 + (((size_t)sb) << 6) + (fl << 2));
            b0 += wa * bf2f((u16)qa)         + wb * bf2f((u16)qb);
            b1 += wa * bf2f((u16)(qa >> 16)) + wb * bf2f((u16)(qb >> 16));
            b2 += wa * bf2f((u16)(qa >> 32)) + wb * bf2f((u16)(qb >> 32));
            b3 += wa * bf2f((u16)(qa >> 48)) + wb * bf2f((u16)(qb >> 48));
        }
    }
    float v0 = f0 * dout + b0 * din;
    float v1 = f1 * dout + b1 * din;
    float v2 = f2 * dout + b2 * din;
    float v3 = f3 * dout + b3 * din;
    v0 += __shfl_xor(v0, 16); v0 += __shfl_xor(v0, 32);
    v1 += __shfl_xor(v1, 16); v1 += __shfl_xor(v1, 32);
    v2 += __shfl_xor(v2, 16); v2 += __shfl_xor(v2, 32);
    v3 += __shfl_xor(v3, 16); v3 += __shfl_xor(v3, 32);
    if (g == 0) {
        float4 bs = *(const float4*)&b_src[fl << 2];
        float4 bd = *(const float4*)&b_dst[fl << 2];
        f32x4 o;
        o.x = v0 + ALPHA * bs.x + (1.f - ALPHA) * bd.x;
        o.y = v1 + ALPHA * bs.y + (1.f - ALPHA) * bd.y;
        o.z = v2 + ALPHA * bs.z + (1.f - ALPHA) * bd.z;
        o.w = v3 + ALPHA * bs.w + (1.f - ALPHA) * bd.w;
        __builtin_nontemporal_store(o, (f32x4*)&out[((size_t)node << 6) + (fl << 2)]);
    }
}

extern "C" void kernel_launch(void* const* d_in, const int* in_sizes, int n_in,
                              void* d_out, int out_size, void* d_ws, size_t ws_size,
                              hipStream_t stream) {
    const float* x     = (const float*)d_in[0];
    const int*   ei    = (const int*)d_in[1];
    const float* w     = (const float*)d_in[2];
    const float* W_src = (const float*)d_in[3];
    const float* b_src = (const float*)d_in[4];
    const float* W_dst = (const float*)d_in[5];
    const float* b_dst = (const float*)d_in[6];
    float* out = (float*)d_out;

    const int N = in_sizes[0] / D;
    const int E = in_sizes[2];
    const int* row = ei;
    const int* col = ei + E;
    const int L = 2 * N;
    const int NCH   = (E + CE - 1) / CE;          // chunks (782)
    const int NBUCK = (L + BN - 1) >> BSH;        // buckets (391), must be <= 512
    const int SZ    = NBUCK * NCH;                // count-matrix size (~306k)
    const int NSB   = (SZ + 511) / 512;           // scan blocks (598), must be <= 1024
    const int total = 2 * E;

    // workspace layout (~81 MB)
    char* base = (char*)d_ws;
    size_t o = 0;
    auto take = [&](size_t b) { char* p = base + o; o = (o + b + 63) & ~(size_t)63; return p; };
    int*    bh      = (int*)take((size_t)SZ * 4);
    int*    scanned = (int*)take((size_t)SZ * 4);
    int*    bsum    = (int*)take(1024 * 4);
    u64*    ent     = (u64*)take((size_t)total * 8);
    float*  dinv    = (float*)take((size_t)L * 4);
    int*    ptr     = (int*)take((size_t)(L + 1) * 4);
    u16*    y1      = (u16*)take((size_t)N * D * 2);
    u16*    y2      = (u16*)take((size_t)N * D * 2);
    float2* edata   = (float2*)take((size_t)total * 8);

    // 1. bucket histogram per chunk (LDS atomics only)
    p1_hist_kernel<<<NCH, 512, 0, stream>>>(row, col, bh, N, E, NCH, NBUCK);
    // 2. exclusive scan of [bucket][chunk] counts
    scan1i_kernel<<<NSB, 512, 0, stream>>>(bh, bsum, SZ);
    scan2w_kernel<<<1, 1024, 0, stream>>>(bsum, NSB);
    scan3i_kernel<<<NSB, 512, 0, stream>>>(bh, bsum, scanned, SZ);
    // 3. chunk-local counting sort -> bucket-major entries, coalesced run writes
    p3_sort_kernel<<<NCH, 512, 0, stream>>>(row, col, w, scanned, ent, N, E, NCH, NBUCK);
    // 4. per-bucket node histogram -> dinv, CSR ptr, edata (L2-local scatter)
    p4_build_kernel<<<NBUCK, 512, 0, stream>>>(ent, scanned, dinv, ptr, edata,
                                               L, NCH, NBUCK, total);
    // 5. register-tiled transform with src-side dinv folded into y
    transform2r_kernel<<<(N + 63) / 64, 256, 0, stream>>>(x, W_src, W_dst, dinv, y1, y2, N);
    // 6. gather with node-side dinv, single out write
    gather_csr_kernel<<<(N + 3) / 4, 256, 0, stream>>>(ptr, dinv, edata, y1, y2,
                                                       b_src, b_dst, out, N);
}

// Round 13
// 217.141 us; speedup vs baseline: 1.8431x; 1.0763x over previous
//
#include <hip/hip_runtime.h>

#define D 64
#define ALPHA 0.5f
#define FXSCALE 16777216.f   // 2^24 fixed-point quantum for degree accumulation
#define CE 2048              // edges per chunk (P1/P3 block)
#define BSH 9                // log2(nodes per bucket)
#define BN 512               // nodes per bucket

typedef unsigned long long u64;
typedef unsigned short u16;
typedef unsigned int u32;
typedef float f32x4 __attribute__((ext_vector_type(4)));

static __device__ __forceinline__ u16 f2bf(float f) {
    unsigned u = __float_as_uint(f);
    unsigned r = (u + 0x7fffu + ((u >> 16) & 1u)) >> 16;
    return (u16)r;
}
static __device__ __forceinline__ float bf2f(u16 h) {
    return __uint_as_float(((unsigned)h) << 16);
}
static __device__ __forceinline__ float dinv_of_fx(u32 fx) {
    float s = (float)fx * (1.f / FXSCALE);
    return (s > 0.f) ? rsqrtf(s) : 0.f;
}

// P1: per-chunk histogram over buckets (dst in [0,2N), bucket = dst>>9)
__global__ void p1_hist_kernel(const int* __restrict__ row, const int* __restrict__ col,
                               int* __restrict__ bh, int N, int E, int NCH, int NBUCK) {
    __shared__ u32 h[512];
    int t = threadIdx.x, ch = blockIdx.x;
    h[t] = 0;
    __syncthreads();
    int e0 = ch * CE, e1 = min(E, e0 + CE);
    for (int e = e0 + t; e < e1; e += 512) {
        atomicAdd(&h[(u32)row[e] >> BSH], 1u);
        atomicAdd(&h[(u32)(N + col[e]) >> BSH], 1u);
    }
    __syncthreads();
    for (int b = t; b < NBUCK; b += 512)
        bh[(size_t)b * NCH + ch] = (int)h[b];   // bucket-major layout
}

// ---- scans over the [bucket][chunk] count matrix (SZ = NBUCK*NCH) ----
__global__ void scan1i_kernel(const int* __restrict__ src, int* __restrict__ bsum, int SZ) {
    __shared__ int s[512];
    int t = threadIdx.x;
    int i = blockIdx.x * 512 + t;
    s[t] = (i < SZ) ? src[i] : 0;
    __syncthreads();
    for (int off = 256; off; off >>= 1) {
        if (t < off) s[t] += s[t + off];
        __syncthreads();
    }
    if (t == 0) bsum[blockIdx.x] = s[0];
}

__global__ void scan2w_kernel(int* __restrict__ bsum, int nb) {   // nb <= 1024
    __shared__ int s[1024];
    int t = threadIdx.x;
    int v = (t < nb) ? bsum[t] : 0;
    s[t] = v;
    __syncthreads();
    for (int off = 1; off < 1024; off <<= 1) {
        int u = (t >= off) ? s[t - off] : 0;
        __syncthreads();
        s[t] += u;
        __syncthreads();
    }
    if (t < nb) bsum[t] = s[t] - v;   // exclusive block offsets
}

__global__ void scan3i_kernel(const int* __restrict__ src, const int* __restrict__ bsum,
                              int* __restrict__ dst, int SZ) {
    __shared__ int s[512];
    int t = threadIdx.x;
    int i = blockIdx.x * 512 + t;
    int v = (i < SZ) ? src[i] : 0;
    s[t] = v;
    __syncthreads();
    for (int off = 1; off < 512; off <<= 1) {
        int u = (t >= off) ? s[t - off] : 0;
        __syncthreads();
        s[t] += u;
        __syncthreads();
    }
    if (i < SZ) dst[i] = bsum[blockIdx.x] + s[t] - v;
}

// Fused heterogeneous kernel: P3 chunk-sort blocks + transform tiles.
// LDS union (u64 slots):  P3: ebuf[0,4096) ebkt[4096,5120) hc[5120,5376)
// hstart[5376,5632) hoff[5632,5888) s[5888,6144)   (ebkt = 4096 u16 = 1024 u64!)
// transform: xs+Wt1+Wt2 = 12864 floats = 6432 u64.
__global__ __launch_bounds__(512)
void p3_transform_kernel(const int* __restrict__ row, const int* __restrict__ col,
                         const float* __restrict__ w, const int* __restrict__ scanned,
                         u64* __restrict__ ent,
                         const float* __restrict__ x,
                         const float* __restrict__ Ws, const float* __restrict__ Wd,
                         u16* __restrict__ y1, u16* __restrict__ y2,
                         int N, int E, int NCH, int NBUCK, int NT, int total_blocks) {
    __shared__ u64 smem[6432];
    int b = blockIdx.x;
    int t = threadIdx.x;
    // Bresenham spread: exactly NT transform blocks evenly interleaved
    int t_before = (int)(((long long)b * NT) / total_blocks);
    bool is_t = (int)(((long long)(b + 1) * NT) / total_blocks) > t_before;

    if (!is_t) {
        // ---------------- P3 sort role ----------------
        int ch = b - t_before;
        u64* ebuf   = smem;                    // [4096] u64
        u16* ebkt   = (u16*)(smem + 4096);     // [4096] u16 -> 1024 u64 slots
        u32* hc     = (u32*)(smem + 5120);     // [512] u32 -> 256 slots
        u32* hstart = (u32*)(smem + 5376);     // [512]
        u32* hoff   = (u32*)(smem + 5632);     // [512]
        int* s      = (int*)(smem + 5888);     // [512]
        hc[t] = 0;
        __syncthreads();
        int e0 = ch * CE, e1 = min(E, e0 + CE);
        for (int e = e0 + t; e < e1; e += 512) {
            atomicAdd(&hc[(u32)row[e] >> BSH], 1u);
            atomicAdd(&hc[(u32)(N + col[e]) >> BSH], 1u);
        }
        __syncthreads();
        int v = (int)hc[t];
        s[t] = v;
        __syncthreads();
        for (int off = 1; off < 512; off <<= 1) {
            int u = (t >= off) ? s[t - off] : 0;
            __syncthreads();
            s[t] += u;
            __syncthreads();
        }
        hstart[t] = (u32)(s[t] - v);
        hoff[t]   = (u32)(s[t] - v);
        hc[t] = (t < NBUCK) ? (u32)scanned[(size_t)t * NCH + ch] : 0u;
        __syncthreads();
        for (int e = e0 + t; e < e1; e += 512) {
            int r = row[e], c = col[e];
            u32 wb = __float_as_uint(w[e]);
            u32 b1 = (u32)r >> BSH;
            u64 q1 = ((u64)wb << 32) | ((u32)c << BSH) | ((u32)r & (BN - 1));
            u32 p1 = atomicAdd(&hoff[b1], 1u);
            ebuf[p1] = q1; ebkt[p1] = (u16)b1;
            u32 d2 = (u32)(N + c);
            u32 b2 = d2 >> BSH;
            u64 q2 = ((u64)wb << 32) | ((u32)r << BSH) | (d2 & (BN - 1));
            u32 p2 = atomicAdd(&hoff[b2], 1u);
            ebuf[p2] = q2; ebkt[p2] = (u16)b2;
        }
        __syncthreads();
        int nent = 2 * (e1 - e0);
        for (int p = t; p < nent; p += 512) {
            u32 bb = ebkt[p];
            ent[(size_t)hc[bb] + (u32)p - hstart[bb]] = ebuf[p];
        }
        return;
    }

    // ---------------- transform role (64-row tile, 512 threads) ----------------
    float* xs  = (float*)smem;            // [64][65]
    float* Wt1 = xs + 64 * 65;            // [64][68] (272B row: float4-aligned)
    float* Wt2 = Wt1 + 64 * 68;
    for (int i = t; i < 4096; i += 512) {
        int o = i >> 6, k = i & 63;
        Wt1[k * 68 + o] = Ws[i];
        Wt2[k * 68 + o] = Wd[i];
    }
    int r0 = t_before * 64;
    for (int i = t; i < 4096; i += 512) {
        int r = i >> 6, k = i & 63;
        int gr = r0 + r;
        xs[r * 65 + k] = (gr < N) ? x[(size_t)gr * D + k] : 0.f;
    }
    __syncthreads();
    int ro = t >> 4, co = t & 15;        // ro 0..31 (2 rows each), co 0..15 (4 cols)
    float a1[2][4] = {}, a2[2][4] = {};
#pragma unroll 4
    for (int k = 0; k < 64; ++k) {
        float v0 = xs[(ro * 2 + 0) * 65 + k];
        float v1 = xs[(ro * 2 + 1) * 65 + k];
        float4 b1 = *(const float4*)&Wt1[k * 68 + co * 4];
        float4 b2 = *(const float4*)&Wt2[k * 68 + co * 4];
        a1[0][0] += v0 * b1.x; a1[0][1] += v0 * b1.y; a1[0][2] += v0 * b1.z; a1[0][3] += v0 * b1.w;
        a1[1][0] += v1 * b1.x; a1[1][1] += v1 * b1.y; a1[1][2] += v1 * b1.z; a1[1][3] += v1 * b1.w;
        a2[0][0] += v0 * b2.x; a2[0][1] += v0 * b2.y; a2[0][2] += v0 * b2.z; a2[0][3] += v0 * b2.w;
        a2[1][0] += v1 * b2.x; a2[1][1] += v1 * b2.y; a2[1][2] += v1 * b2.z; a2[1][3] += v1 * b2.w;
    }
#pragma unroll
    for (int i = 0; i < 2; ++i) {
        int gr = r0 + ro * 2 + i;
        if (gr < N) {
            ushort4 o1, o2;
            o1.x = f2bf(a1[i][0] * ALPHA); o1.y = f2bf(a1[i][1] * ALPHA);
            o1.z = f2bf(a1[i][2] * ALPHA); o1.w = f2bf(a1[i][3] * ALPHA);
            o2.x = f2bf(a2[i][0] * (1.f - ALPHA)); o2.y = f2bf(a2[i][1] * (1.f - ALPHA));
            o2.z = f2bf(a2[i][2] * (1.f - ALPHA)); o2.w = f2bf(a2[i][3] * (1.f - ALPHA));
            *(ushort4*)&y1[(size_t)gr * D + co * 4] = o1;
            *(ushort4*)&y2[(size_t)gr * D + co * 4] = o2;
        }
    }
}

// P4: per-bucket node histogram (counts + fixed-point weighted degree), CSR ptr,
// dinv, and edata fill (src, w_raw) — scatter confined to an L2-resident window.
__global__ void p4_build_kernel(const u64* __restrict__ ent, const int* __restrict__ scanned,
                                float* __restrict__ dinv, int* __restrict__ ptr,
                                float2* __restrict__ edata,
                                int L, int NCH, int NBUCK, int total) {
    __shared__ u32 cnt[512], fx[512], pstart[512], pfill[512];
    __shared__ int s[512];
    int t = threadIdx.x, b = blockIdx.x;
    int base0 = scanned[(size_t)b * NCH];
    int base1 = (b + 1 < NBUCK) ? scanned[(size_t)(b + 1) * NCH] : total;
    int nE = base1 - base0;
    cnt[t] = 0; fx[t] = 0;
    __syncthreads();
    for (int i = t; i < nE; i += 512) {
        u64 q = ent[base0 + i];
        u32 dlo = (u32)q & (BN - 1);
        float wv = __uint_as_float((u32)(q >> 32));
        atomicAdd(&cnt[dlo], 1u);
        atomicAdd(&fx[dlo], (u32)__float2uint_rn(wv * FXSCALE));
    }
    __syncthreads();
    int v = (int)cnt[t];
    s[t] = v;
    __syncthreads();
    for (int off = 1; off < 512; off <<= 1) {
        int u = (t >= off) ? s[t - off] : 0;
        __syncthreads();
        s[t] += u;
        __syncthreads();
    }
    pstart[t] = (u32)(s[t] - v);
    pfill[t]  = (u32)(s[t] - v);
    int node = b * BN + t;
    if (node < L) {
        dinv[node] = dinv_of_fx(fx[t]);
        ptr[node] = base0 + (int)pstart[t];
    }
    if (b == 0 && t == 0) ptr[L] = total;
    __syncthreads();
    for (int i = t; i < nE; i += 512) {
        u64 q = ent[base0 + i];
        u32 dlo = (u32)q & (BN - 1);
        u32 src = ((u32)q) >> BSH;
        float wv = __uint_as_float((u32)(q >> 32));
        u32 pos = atomicAdd(&pfill[dlo], 1u);
        edata[base0 + pos] = make_float2(__int_as_float((int)src), wv);
    }
}

// gather: one wave per node; 64 lanes = 4 edge-slots x 16 feature-slots.
// 16 edges per iteration (4 independent chains). Per-edge src-side dinv read
// (800 KB, L2-resident). Node-side dinv scalars applied at the end.
__global__ void gather_csr_kernel(const int* __restrict__ ptr, const float* __restrict__ dinv,
                                  const float2* __restrict__ ed,
                                  const u16* __restrict__ y1, const u16* __restrict__ y2,
                                  const float* __restrict__ b_src, const float* __restrict__ b_dst,
                                  float* __restrict__ out, int N) {
    int tid = threadIdx.x;
    int lane = tid & 63;
    int node = blockIdx.x * (blockDim.x >> 6) + (tid >> 6);
    if (node >= N) return;
    int g  = lane >> 4;
    int fl = lane & 15;

    float v0 = 0.f, v1 = 0.f, v2 = 0.f, v3 = 0.f;
#pragma unroll
    for (int dir = 0; dir < 2; ++dir) {
        const u16* __restrict__ y = dir ? y2 : y1;
        const float* __restrict__ ds = dir ? dinv : dinv + N;   // src-side dinv base
        int e0 = ptr[dir * N + node], e1 = ptr[dir * N + node + 1];
        float c0 = 0.f, c1 = 0.f, c2 = 0.f, c3 = 0.f;
        for (int eb = e0; eb < e1; eb += 16) {
            int ea = eb + g, eb2 = eb + 4 + g, ec = eb + 8 + g, ee = eb + 12 + g;
            float2 da = (ea  < e1) ? ed[ea]  : make_float2(__int_as_float(0), 0.f);
            float2 db = (eb2 < e1) ? ed[eb2] : make_float2(__int_as_float(0), 0.f);
            float2 dc = (ec  < e1) ? ed[ec]  : make_float2(__int_as_float(0), 0.f);
            float2 de = (ee  < e1) ? ed[ee]  : make_float2(__int_as_float(0), 0.f);
            int sa = __float_as_int(da.x), sb = __float_as_int(db.x);
            int sc = __float_as_int(dc.x), se = __float_as_int(de.x);
            float wa = da.y * ds[sa], wb = db.y * ds[sb];
            float wc = dc.y * ds[sc], we = de.y * ds[se];
            u64 qa = *(const u64*)(y + (((size_t)sa) << 6) + (fl << 2));
            u64 qb = *(const u64*)(y + (((size_t)sb) << 6) + (fl << 2));
            u64 qc = *(const u64*)(y + (((size_t)sc) << 6) + (fl << 2));
            u64 qe = *(const u64*)(y + (((size_t)se) << 6) + (fl << 2));
            c0 += wa * bf2f((u16)qa)         + wb * bf2f((u16)qb)
                + wc * bf2f((u16)qc)         + we * bf2f((u16)qe);
            c1 += wa * bf2f((u16)(qa >> 16)) + wb * bf2f((u16)(qb >> 16))
                + wc * bf2f((u16)(qc >> 16)) + we * bf2f((u16)(qe >> 16));
            c2 += wa * bf2f((u16)(qa >> 32)) + wb * bf2f((u16)(qb >> 32))
                + wc * bf2f((u16)(qc >> 32)) + we * bf2f((u16)(qe >> 32));
            c3 += wa * bf2f((u16)(qa >> 48)) + wb * bf2f((u16)(qb >> 48))
                + wc * bf2f((u16)(qc >> 48)) + we * bf2f((u16)(qe >> 48));
        }
        float scale = dinv[dir * N + node];   // dst-side: dout for fwd, din for bwd
        v0 += c0 * scale; v1 += c1 * scale; v2 += c2 * scale; v3 += c3 * scale;
    }
    v0 += __shfl_xor(v0, 16); v0 += __shfl_xor(v0, 32);
    v1 += __shfl_xor(v1, 16); v1 += __shfl_xor(v1, 32);
    v2 += __shfl_xor(v2, 16); v2 += __shfl_xor(v2, 32);
    v3 += __shfl_xor(v3, 16); v3 += __shfl_xor(v3, 32);
    if (g == 0) {
        float4 bs = *(const float4*)&b_src[fl << 2];
        float4 bd = *(const float4*)&b_dst[fl << 2];
        f32x4 o;
        o.x = v0 + ALPHA * bs.x + (1.f - ALPHA) * bd.x;
        o.y = v1 + ALPHA * bs.y + (1.f - ALPHA) * bd.y;
        o.z = v2 + ALPHA * bs.z + (1.f - ALPHA) * bd.z;
        o.w = v3 + ALPHA * bs.w + (1.f - ALPHA) * bd.w;
        __builtin_nontemporal_store(o, (f32x4*)&out[((size_t)node << 6) + (fl << 2)]);
    }
}

extern "C" void kernel_launch(void* const* d_in, const int* in_sizes, int n_in,
                              void* d_out, int out_size, void* d_ws, size_t ws_size,
                              hipStream_t stream) {
    const float* x     = (const float*)d_in[0];
    const int*   ei    = (const int*)d_in[1];
    const float* w     = (const float*)d_in[2];
    const float* W_src = (const float*)d_in[3];
    const float* b_src = (const float*)d_in[4];
    const float* W_dst = (const float*)d_in[5];
    const float* b_dst = (const float*)d_in[6];
    float* out = (float*)d_out;

    const int N = in_sizes[0] / D;
    const int E = in_sizes[2];
    const int* row = ei;
    const int* col = ei + E;
    const int L = 2 * N;
    const int NCH   = (E + CE - 1) / CE;          // chunks (782)
    const int NBUCK = (L + BN - 1) >> BSH;        // buckets (391), must be <= 512
    const int SZ    = NBUCK * NCH;                // count-matrix size (~306k)
    const int NSB   = (SZ + 511) / 512;           // scan blocks (598), must be <= 1024
    const int NT    = (N + 63) / 64;              // transform tiles (1563)
    const int total = 2 * E;

    // workspace layout (~81 MB)
    char* base = (char*)d_ws;
    size_t o = 0;
    auto take = [&](size_t b) { char* p = base + o; o = (o + b + 63) & ~(size_t)63; return p; };
    int*    bh      = (int*)take((size_t)SZ * 4);
    int*    scanned = (int*)take((size_t)SZ * 4);
    int*    bsum    = (int*)take(1024 * 4);
    u64*    ent     = (u64*)take((size_t)total * 8);
    float*  dinv    = (float*)take((size_t)L * 4);
    int*    ptr     = (int*)take((size_t)(L + 1) * 4);
    u16*    y1      = (u16*)take((size_t)N * D * 2);
    u16*    y2      = (u16*)take((size_t)N * D * 2);
    float2* edata   = (float2*)take((size_t)total * 8);

    // 1. bucket histogram per chunk (LDS atomics only)
    p1_hist_kernel<<<NCH, 512, 0, stream>>>(row, col, bh, N, E, NCH, NBUCK);
    // 2. exclusive scan of [bucket][chunk] counts
    scan1i_kernel<<<NSB, 512, 0, stream>>>(bh, bsum, SZ);
    scan2w_kernel<<<1, 1024, 0, stream>>>(bsum, NSB);
    scan3i_kernel<<<NSB, 512, 0, stream>>>(bh, bsum, scanned, SZ);
    // 3. fused: chunk-local counting sort + transform tiles (independent pipes)
    p3_transform_kernel<<<NCH + NT, 512, 0, stream>>>(row, col, w, scanned, ent,
                                                      x, W_src, W_dst, y1, y2,
                                                      N, E, NCH, NBUCK, NT, NCH + NT);
    // 4. per-bucket node histogram -> dinv, CSR ptr, edata (L2-local scatter)
    p4_build_kernel<<<NBUCK, 512, 0, stream>>>(ent, scanned, dinv, ptr, edata,
                                               L, NCH, NBUCK, total);
    // 5. gather: src-side dinv per edge, dst-side dinv scalars, single out write
    gather_csr_kernel<<<(N + 3) / 4, 256, 0, stream>>>(ptr, dinv, edata, y1, y2,
                                                       b_src, b_dst, out, N);
}